// Round 1
// baseline (153.246 us; speedup 1.0000x reference)
//
#include <hip/hip_runtime.h>

#define D 128

__global__ __launch_bounds__(256) void transe_time_kernel(
    const int* __restrict__ idx,      // (B,5) int32
    const float* __restrict__ ent,    // (500000,128)
    const float* __restrict__ rel,    // (1000,128)
    const float* __restrict__ tt,     // (1000,16384)
    float* __restrict__ out, int B)
{
    const int b = blockIdx.x;
    if (b >= B) return;
    const int tid = threadIdx.x;
    const int e4  = tid & 31;   // column quad: e = e4*4 .. e4*4+3
    const int g   = tid >> 5;   // row group 0..7

    __shared__ float sh_h[D];
    __shared__ float sh_t[D];
    __shared__ float ph[8][D];
    __shared__ float pt[8][D];
    __shared__ float wred[8];

    const int hi = idx[b * 5 + 0];
    const int ri = idx[b * 5 + 1];
    const int ti = idx[b * 5 + 2];
    const int si = idx[b * 5 + 3];
    const int ei = idx[b * 5 + 4];

    if (tid < D) {
        sh_h[tid] = ent[(size_t)hi * D + tid];
        sh_t[tid] = ent[(size_t)ti * D + tid];
    }
    __syncthreads();

    const float4* __restrict__ Ts = (const float4*)(tt + (size_t)si * D * D);
    const float4* __restrict__ Te = (const float4*)(tt + (size_t)ei * D * D);

    float4 hacc = make_float4(0.f, 0.f, 0.f, 0.f);
    float4 tacc = make_float4(0.f, 0.f, 0.f, 0.f);

    // each row-group g covers d = d0+g, d0 stepping by 8; 16 iterations
    #pragma unroll 4
    for (int d0 = 0; d0 < D; d0 += 8) {
        const int d = d0 + g;
        const float4 a = Ts[d * 32 + e4];
        const float4 c = Te[d * 32 + e4];
        const float hd = sh_h[d];
        const float td = sh_t[d];
        const float mx = a.x + c.x;
        const float my = a.y + c.y;
        const float mz = a.z + c.z;
        const float mw = a.w + c.w;
        hacc.x += hd * mx; hacc.y += hd * my; hacc.z += hd * mz; hacc.w += hd * mw;
        tacc.x += td * mx; tacc.y += td * my; tacc.z += td * mz; tacc.w += td * mw;
    }

    ((float4*)ph[g])[e4] = hacc;
    ((float4*)pt[g])[e4] = tacc;
    __syncthreads();

    // threads 0..127 each own one output column e = tid
    float h2 = 0.f, t2 = 0.f;
    if (tid < D) {
        #pragma unroll
        for (int k = 0; k < 8; ++k) {
            h2 += ph[k][tid];
            t2 += pt[k][tid];
        }
    }

    // block-wide sum of squares (threads >= 128 contribute 0)
    float nh = h2 * h2;
    float nt = t2 * t2;
    #pragma unroll
    for (int off = 32; off; off >>= 1) {
        nh += __shfl_down(nh, off, 64);
        nt += __shfl_down(nt, off, 64);
    }
    const int wv = tid >> 6;          // wave id 0..3
    if ((tid & 63) == 0) { wred[wv * 2] = nh; wred[wv * 2 + 1] = nt; }
    __syncthreads();
    const float NH = wred[0] + wred[2] + wred[4] + wred[6];
    const float NT = wred[1] + wred[3] + wred[5] + wred[7];
    const float rnh = 1.0f / fmaxf(sqrtf(NH), 1e-12f);
    const float rnt = 1.0f / fmaxf(sqrtf(NT), 1e-12f);

    float v = 0.f;
    if (tid < D) {
        const float rr = rel[(size_t)ri * D + tid];
        v = fabsf(h2 * rnh + rr - t2 * rnt + 1e-6f);
    }
    #pragma unroll
    for (int off = 32; off; off >>= 1) v += __shfl_down(v, off, 64);
    __syncthreads();                   // reuse wred safely
    if ((tid & 63) == 0) wred[wv] = v;
    __syncthreads();
    if (tid == 0) out[b] = wred[0] + wred[1] + wred[2] + wred[3];
}

extern "C" void kernel_launch(void* const* d_in, const int* in_sizes, int n_in,
                              void* d_out, int out_size, void* d_ws, size_t ws_size,
                              hipStream_t stream) {
    const int*   idx = (const int*)d_in[0];
    const float* ent = (const float*)d_in[1];
    const float* rel = (const float*)d_in[2];
    const float* tt  = (const float*)d_in[3];
    float* out = (float*)d_out;
    const int B = in_sizes[0] / 5;

    transe_time_kernel<<<dim3(B), dim3(256), 0, stream>>>(idx, ent, rel, tt, out, B);
}